// Round 1
// baseline (296.834 us; speedup 1.0000x reference)
//
#include <hip/hip_runtime.h>
#include <math.h>

#define BB 8
#define CC 256
#define HH 128
#define WW 128
#define HWP 16384   // 128*128
#define MH 512
#define MW 512
#define NPIX (BB*HWP)   // 131072

// ---------------------------------------------------------------------------
// Kernel 1: bilinear (antialias) downsample masks [B,512,512] -> m [B,128,128]
// jax.image.resize semantics: triangle kernel scaled by 4, sample at 4i+1.5,
// taps k = 4i-2 .. 4i+5 with raw weights {1,3,5,7,7,5,3,1}, OOB taps dropped
// and remaining renormalized (separably).
// ---------------------------------------------------------------------------
__global__ __launch_bounds__(256) void kmask(const float* __restrict__ masks,
                                             float* __restrict__ m_out) {
    int t = blockIdx.x * 256 + threadIdx.x;
    int j = t & 127, i = (t >> 7) & 127, b = t >> 14;
    const float Wt[8] = {1.f, 3.f, 5.f, 7.f, 7.f, 5.f, 3.f, 1.f};
    const float* mb = masks + (size_t)b * MH * MW;
    int r0 = 4 * i - 2, c0 = 4 * j - 2;
    float sh = 0.f;
    #pragma unroll
    for (int q = 0; q < 8; q++) {
        int c = c0 + q;
        if (c >= 0 && c < MW) sh += Wt[q];
    }
    float sv = 0.f, acc = 0.f;
    #pragma unroll
    for (int p = 0; p < 8; p++) {
        int r = r0 + p;
        if (r < 0 || r >= MH) continue;
        sv += Wt[p];
        const float* row = mb + (size_t)r * MW;
        float ra = 0.f;
        #pragma unroll
        for (int q = 0; q < 8; q++) {
            int c = c0 + q;
            if (c >= 0 && c < MW) ra += Wt[q] * row[c];
        }
        acc += Wt[p] * ra;
    }
    m_out[t] = acc / (sv * sh);
}

// ---------------------------------------------------------------------------
// Kernel 2: channel reduction over x: per-pixel sum and max over a 128-channel
// half (g=0/1).  cs/cm layout: [2][B*HWP].
// ---------------------------------------------------------------------------
__global__ __launch_bounds__(256) void kreduce(const float* __restrict__ x,
                                               float* __restrict__ cs,
                                               float* __restrict__ cm) {
    int bid = blockIdx.x;
    int chunk = bid & 63;
    int g = (bid >> 6) & 1;
    int b = bid >> 7;
    int pix = chunk * 256 + threadIdx.x;
    const float* base = x + ((size_t)b * CC + g * 128) * HWP + pix;
    float s = 0.f, mx = -INFINITY;
    #pragma unroll 8
    for (int c = 0; c < 128; c++) {
        float v = base[(size_t)c * HWP];
        s += v;
        mx = fmaxf(mx, v);
    }
    int o = g * NPIX + b * HWP + pix;
    cs[o] = s;
    cm[o] = mx;
}

// ---------------------------------------------------------------------------
// Kernel 3: combine halves into avg_out = m * sum/256, max_out = m * max
// ---------------------------------------------------------------------------
__global__ __launch_bounds__(256) void kprep(const float* __restrict__ m,
                                             const float* __restrict__ cs,
                                             const float* __restrict__ cm,
                                             float* __restrict__ avgo,
                                             float* __restrict__ maxo) {
    int t = blockIdx.x * 256 + threadIdx.x;
    float mm = m[t];
    float s = cs[t] + cs[t + NPIX];
    float mxx = fmaxf(cm[t], cm[t + NPIX]);
    avgo[t] = mm * (s * (1.f / 256.f));
    maxo[t] = mm * mxx;
}

// ---------------------------------------------------------------------------
// Kernel 4: 7x7 conv (cross-correlation, zero-pad 3) over [avg,max,m],
// sigmoid, then wprod = m * atten
// ---------------------------------------------------------------------------
__global__ __launch_bounds__(256) void kconv(const float* __restrict__ avgo,
                                             const float* __restrict__ maxo,
                                             const float* __restrict__ m,
                                             const float* __restrict__ cw,
                                             float* __restrict__ wprod) {
    __shared__ float w[147];
    if (threadIdx.x < 147) w[threadIdx.x] = cw[threadIdx.x];
    __syncthreads();
    int t = blockIdx.x * 256 + threadIdx.x;
    int j = t & 127, i = (t >> 7) & 127, b = t >> 14;
    const float* arrs[3] = {avgo, maxo, m};
    float acc = 0.f;
    for (int ch = 0; ch < 3; ch++) {
        const float* a = arrs[ch] + (size_t)b * HWP;
        #pragma unroll
        for (int di = -3; di <= 3; di++) {
            int ii = i + di;
            if (ii < 0 || ii >= HH) continue;
            #pragma unroll
            for (int dj = -3; dj <= 3; dj++) {
                int jj = j + dj;
                if (jj < 0 || jj >= WW) continue;
                acc += w[ch * 49 + (di + 3) * 7 + (dj + 3)] * a[ii * WW + jj];
            }
        }
    }
    float at = 1.f / (1.f + expf(-acc));
    wprod[t] = m[t] * at;
}

// ---------------------------------------------------------------------------
// Kernel 5: final. One block per (b,c) plane. o = x*wprod cached in registers
// (16 float4/thread), block-reduce mean/var, instance-norm + relu(5*).
// ---------------------------------------------------------------------------
__global__ __launch_bounds__(256) void kfinal(const float* __restrict__ x,
                                              const float* __restrict__ wprod,
                                              const float* __restrict__ gamma,
                                              const float* __restrict__ beta,
                                              float* __restrict__ out) {
    int bc = blockIdx.x;          // b*256 + c
    int b = bc >> 8, c = bc & 255;
    const float4* xp = (const float4*)(x + (size_t)bc * HWP);
    const float4* wp = (const float4*)(wprod + (size_t)b * HWP);
    float4 o[16];
    float s = 0.f, ss = 0.f;
    #pragma unroll
    for (int k = 0; k < 16; k++) {
        int idx = threadIdx.x + k * 256;
        float4 xv = xp[idx];
        float4 wv = wp[idx];
        float4 ov;
        ov.x = xv.x * wv.x;
        ov.y = xv.y * wv.y;
        ov.z = xv.z * wv.z;
        ov.w = xv.w * wv.w;
        o[k] = ov;
        s += ov.x + ov.y + ov.z + ov.w;
        ss += ov.x * ov.x + ov.y * ov.y + ov.z * ov.z + ov.w * ov.w;
    }
    // wave (64-lane) reduction
    #pragma unroll
    for (int off = 32; off; off >>= 1) {
        s += __shfl_down(s, off, 64);
        ss += __shfl_down(ss, off, 64);
    }
    __shared__ float ls[4], lss[4];
    __shared__ float smu, srs;
    int wave = threadIdx.x >> 6, lane = threadIdx.x & 63;
    if (lane == 0) { ls[wave] = s; lss[wave] = ss; }
    __syncthreads();
    if (threadIdx.x == 0) {
        float S = ls[0] + ls[1] + ls[2] + ls[3];
        float SS = lss[0] + lss[1] + lss[2] + lss[3];
        float mu = S * (1.f / HWP);
        float var = fmaxf(SS * (1.f / HWP) - mu * mu, 0.f);
        smu = mu;
        srs = rsqrtf(var + 1e-5f);
    }
    __syncthreads();
    float mu = smu;
    float g5 = 5.f * srs * gamma[c];
    float b5 = 5.f * beta[c];
    float4* op = (float4*)(out + (size_t)bc * HWP);
    #pragma unroll
    for (int k = 0; k < 16; k++) {
        int idx = threadIdx.x + k * 256;
        float4 ov = o[k], r;
        r.x = fmaxf(fmaf(ov.x - mu, g5, b5), 0.f);
        r.y = fmaxf(fmaf(ov.y - mu, g5, b5), 0.f);
        r.z = fmaxf(fmaf(ov.z - mu, g5, b5), 0.f);
        r.w = fmaxf(fmaf(ov.w - mu, g5, b5), 0.f);
        op[idx] = r;
    }
}

extern "C" void kernel_launch(void* const* d_in, const int* in_sizes, int n_in,
                              void* d_out, int out_size, void* d_ws, size_t ws_size,
                              hipStream_t stream) {
    const float* x      = (const float*)d_in[0];
    const float* masks  = (const float*)d_in[1];
    const float* conv_w = (const float*)d_in[2];
    const float* gamma  = (const float*)d_in[3];
    const float* beta   = (const float*)d_in[4];
    float* out = (float*)d_out;

    float* ws = (float*)d_ws;
    float* m_arr  = ws;                 // [NPIX]
    float* cs     = ws + (size_t)NPIX;      // [2*NPIX]
    float* cm     = ws + (size_t)3 * NPIX;  // [2*NPIX]
    float* avgo   = ws + (size_t)5 * NPIX;  // [NPIX]
    float* maxo   = ws + (size_t)6 * NPIX;  // [NPIX]
    float* wprod  = ws + (size_t)7 * NPIX;  // [NPIX]

    kmask<<<NPIX / 256, 256, 0, stream>>>(masks, m_arr);
    kreduce<<<1024, 256, 0, stream>>>(x, cs, cm);
    kprep<<<NPIX / 256, 256, 0, stream>>>(m_arr, cs, cm, avgo, maxo);
    kconv<<<NPIX / 256, 256, 0, stream>>>(avgo, maxo, m_arr, conv_w, wprod);
    kfinal<<<BB * CC, 256, 0, stream>>>(x, wprod, gamma, beta, out);
}

// Round 2
// 266.447 us; speedup vs baseline: 1.1140x; 1.1140x over previous
//
#include <hip/hip_runtime.h>
#include <math.h>

#define BB 8
#define CC 256
#define HH 128
#define WW 128
#define HWP 16384          // 128*128
#define MH 512
#define MW 512
#define NPIX (BB*HWP)      // 131072
#define IQ 4096            // HWP/4 quads per image

// ---------------------------------------------------------------------------
// K1: heterogeneous grid, 1024 blocks interleaved.
//   even blocks (id = bid>>1, 512): antialias 512->128 mask resize, branchless
//   odd  blocks (id = bid>>1, 512): x channel partial sum/max, float4 loads,
//                                   4 groups of 64 channels -> cs/cm [4][NPIX]
// ---------------------------------------------------------------------------
__global__ __launch_bounds__(256) void k1(const float* __restrict__ masks,
                                          const float* __restrict__ x,
                                          float* __restrict__ m_out,
                                          float* __restrict__ cs,
                                          float* __restrict__ cm) {
    int bid = blockIdx.x, tid = threadIdx.x;
    if ((bid & 1) == 0) {
        // ---- mask resize path ----
        int t = (bid >> 1) * 256 + tid;            // 0..NPIX-1
        int j = t & 127, i = (t >> 7) & 127, b = t >> 14;
        const float Wt[8] = {1.f, 3.f, 5.f, 7.f, 7.f, 5.f, 3.f, 1.f};
        const float* mb = masks + (size_t)b * (MH * MW);
        int r0 = 4 * i - 2, c0 = 4 * j - 2;
        float cwgt[8];
        int ccl[8];
        float sh = 0.f;
        #pragma unroll
        for (int q = 0; q < 8; q++) {
            int c = c0 + q;
            bool v = (unsigned)c < (unsigned)MW;
            cwgt[q] = v ? Wt[q] : 0.f;
            sh += cwgt[q];
            ccl[q] = min(max(c, 0), MW - 1);
        }
        float acc = 0.f, sv = 0.f;
        #pragma unroll
        for (int p = 0; p < 8; p++) {
            int r = r0 + p;
            bool v = (unsigned)r < (unsigned)MH;
            float wp = v ? Wt[p] : 0.f;
            sv += wp;
            const float* row = mb + (size_t)min(max(r, 0), MH - 1) * MW;
            float ra = 0.f;
            #pragma unroll
            for (int q = 0; q < 8; q++) ra += cwgt[q] * row[ccl[q]];
            acc += wp * ra;
        }
        m_out[t] = acc / (sv * sh);
    } else {
        // ---- channel partial-reduce path ----
        int id = bid >> 1;               // 0..511 = b(3) | g(2) | chunk(4)
        int chunk = id & 15;
        int g = (id >> 4) & 3;
        int b = id >> 6;
        int qi = chunk * 256 + tid;      // quad index within image, 0..4095
        const float4* xb = (const float4*)x + ((size_t)(b * CC + g * 64)) * IQ + qi;
        float4 s = {0.f, 0.f, 0.f, 0.f};
        float4 mx = {-INFINITY, -INFINITY, -INFINITY, -INFINITY};
        #pragma unroll 8
        for (int c = 0; c < 64; c++) {
            float4 v = xb[(size_t)c * IQ];
            s.x += v.x; s.y += v.y; s.z += v.z; s.w += v.w;
            mx.x = fmaxf(mx.x, v.x); mx.y = fmaxf(mx.y, v.y);
            mx.z = fmaxf(mx.z, v.z); mx.w = fmaxf(mx.w, v.w);
        }
        size_t o = (size_t)g * (NPIX / 4) + (size_t)b * IQ + qi;
        ((float4*)cs)[o] = s;
        ((float4*)cm)[o] = mx;
    }
}

// ---------------------------------------------------------------------------
// K2: fused combine + 7x7 conv + sigmoid -> wprod = m * sigmoid(conv)
// Block = 64x4 output tile, LDS halo 70x10 per plane (avg*m, max*m, m).
// Partials combined ONCE per halo pixel at staging time.
// ---------------------------------------------------------------------------
#define TW 64
#define TH 4
#define IW 70
#define IH 10
#define PITCH 72
__global__ __launch_bounds__(256) void k2(const float* __restrict__ m,
                                          const float* __restrict__ cs,
                                          const float* __restrict__ cm,
                                          const float* __restrict__ cw,
                                          float* __restrict__ wprod) {
    __shared__ float w[147];
    __shared__ float pa[IH * PITCH], px[IH * PITCH], pm[IH * PITCH];
    int tid = threadIdx.x, bid = blockIdx.x;
    int bx = bid & 1, by = (bid >> 1) & 31, b = bid >> 6;
    if (tid < 147) w[tid] = cw[tid];
    int ox = bx * TW - 3, oy = by * TH - 3;
    for (int idx = tid; idx < IW * IH; idx += 256) {
        int r = idx / IW, c = idx - r * IW;
        int gi = oy + r, gj = ox + c;
        float av = 0.f, mxv = 0.f, mv = 0.f;
        if ((unsigned)gi < (unsigned)HH && (unsigned)gj < (unsigned)WW) {
            int p = b * HWP + gi * WW + gj;
            mv = m[p];
            float s = cs[p] + cs[p + NPIX] + cs[p + 2 * NPIX] + cs[p + 3 * NPIX];
            float mmx = fmaxf(fmaxf(cm[p], cm[p + NPIX]),
                              fmaxf(cm[p + 2 * NPIX], cm[p + 3 * NPIX]));
            av = mv * s * (1.f / 256.f);
            mxv = mv * mmx;
        }
        pa[r * PITCH + c] = av;
        px[r * PITCH + c] = mxv;
        pm[r * PITCH + c] = mv;
    }
    __syncthreads();
    int col = tid & 63, r = tid >> 6;
    float acc = 0.f;
    #pragma unroll
    for (int di = 0; di < 7; di++) {
        #pragma unroll
        for (int dj = 0; dj < 7; dj++) {
            int li = (r + di) * PITCH + col + dj;
            acc += w[di * 7 + dj] * pa[li];
            acc += w[49 + di * 7 + dj] * px[li];
            acc += w[98 + di * 7 + dj] * pm[li];
        }
    }
    float at = 1.f / (1.f + expf(-acc));
    float res = pm[(r + 3) * PITCH + col + 3] * at;
    wprod[b * HWP + (by * TH + r) * WW + bx * TW + col] = res;
}

// ---------------------------------------------------------------------------
// K3: final. One block per (b,c) plane. o = x*wprod cached in registers,
// block-reduce mean/var, instance-norm + relu(5*).
// ---------------------------------------------------------------------------
__global__ __launch_bounds__(256) void k3(const float* __restrict__ x,
                                          const float* __restrict__ wprod,
                                          const float* __restrict__ gamma,
                                          const float* __restrict__ beta,
                                          float* __restrict__ out) {
    int bc = blockIdx.x;          // b*256 + c
    int b = bc >> 8, c = bc & 255;
    const float4* xp = (const float4*)(x + (size_t)bc * HWP);
    const float4* wp = (const float4*)(wprod + (size_t)b * HWP);
    float4 o[16];
    float s = 0.f, ss = 0.f;
    #pragma unroll
    for (int k = 0; k < 16; k++) {
        int idx = threadIdx.x + k * 256;
        float4 xv = xp[idx];
        float4 wv = wp[idx];
        float4 ov;
        ov.x = xv.x * wv.x; ov.y = xv.y * wv.y;
        ov.z = xv.z * wv.z; ov.w = xv.w * wv.w;
        o[k] = ov;
        s += ov.x + ov.y + ov.z + ov.w;
        ss += ov.x * ov.x + ov.y * ov.y + ov.z * ov.z + ov.w * ov.w;
    }
    #pragma unroll
    for (int off = 32; off; off >>= 1) {
        s += __shfl_down(s, off, 64);
        ss += __shfl_down(ss, off, 64);
    }
    __shared__ float ls[4], lss[4];
    __shared__ float smu, srs;
    int wave = threadIdx.x >> 6, lane = threadIdx.x & 63;
    if (lane == 0) { ls[wave] = s; lss[wave] = ss; }
    __syncthreads();
    if (threadIdx.x == 0) {
        float S = ls[0] + ls[1] + ls[2] + ls[3];
        float SS = lss[0] + lss[1] + lss[2] + lss[3];
        float mu = S * (1.f / HWP);
        float var = fmaxf(SS * (1.f / HWP) - mu * mu, 0.f);
        smu = mu;
        srs = rsqrtf(var + 1e-5f);
    }
    __syncthreads();
    float mu = smu;
    float g5 = 5.f * srs * gamma[c];
    float b5 = 5.f * beta[c];
    float4* op = (float4*)(out + (size_t)bc * HWP);
    #pragma unroll
    for (int k = 0; k < 16; k++) {
        int idx = threadIdx.x + k * 256;
        float4 ov = o[k], r;
        r.x = fmaxf(fmaf(ov.x - mu, g5, b5), 0.f);
        r.y = fmaxf(fmaf(ov.y - mu, g5, b5), 0.f);
        r.z = fmaxf(fmaf(ov.z - mu, g5, b5), 0.f);
        r.w = fmaxf(fmaf(ov.w - mu, g5, b5), 0.f);
        op[idx] = r;
    }
}

extern "C" void kernel_launch(void* const* d_in, const int* in_sizes, int n_in,
                              void* d_out, int out_size, void* d_ws, size_t ws_size,
                              hipStream_t stream) {
    const float* x      = (const float*)d_in[0];
    const float* masks  = (const float*)d_in[1];
    const float* conv_w = (const float*)d_in[2];
    const float* gamma  = (const float*)d_in[3];
    const float* beta   = (const float*)d_in[4];
    float* out = (float*)d_out;

    float* ws = (float*)d_ws;
    float* m_arr = ws;                       // [NPIX]
    float* cs    = ws + (size_t)NPIX;        // [4*NPIX]
    float* cm    = ws + (size_t)5 * NPIX;    // [4*NPIX]
    float* wprod = ws + (size_t)9 * NPIX;    // [NPIX]

    k1<<<1024, 256, 0, stream>>>(masks, x, m_arr, cs, cm);
    k2<<<512, 256, 0, stream>>>(m_arr, cs, cm, conv_w, wprod);
    k3<<<BB * CC, 256, 0, stream>>>(x, wprod, gamma, beta, out);
}